// Round 7
// baseline (20635.130 us; speedup 1.0000x reference)
//
#include <hip/hip_runtime.h>
#include <hip/hip_bf16.h>
#include <math.h>
#include <stdint.h>

using bf16 = __hip_bfloat16;
typedef __attribute__((ext_vector_type(8))) short short8;   // 8 bf16 (MFMA A/B frag)
typedef __attribute__((ext_vector_type(4))) float floatx4;  // MFMA C/D frag (f32)
typedef __attribute__((ext_vector_type(4))) int int4v;      // i8 K=64 frag / i32 acc

typedef const __attribute__((address_space(1))) void* gptr_t;
typedef __attribute__((address_space(3))) void* lptr_t;

__device__ __forceinline__ void load_lds16(const void* g, void* l) {
    __builtin_amdgcn_global_load_lds((gptr_t)(uintptr_t)g, (lptr_t)(uintptr_t)l, 16, 0, 0);
}

// tanh(x) = 1 - 2/(exp(2x)+1)
__device__ __forceinline__ float fast_tanh(float x) {
    float e = __expf(2.f * x);
    return 1.f - 2.f / (e + 1.f);
}

// ===========================================================================
// Per-RK4-STEP kernels (10 launches), R6's verified body inside.
//
// R6 post-mortem: activations-in-LDS changed nothing (17.9->17.35 GB fetch)
// => the 17 GB is WEIGHT re-fetch. Model fitting R1..R6: a weight line
// survives L2 only if the next block's pass arrives within ~4MB of traffic;
// phase-synced blocks (R1, separate launches) => passes clustered => hits;
// free-running 40-eval kernels (R5/R6) => drift spreads passes => ~50% miss.
// Kernel launches are the only safe synchronizer => bound drift to ONE RK4
// step (4 evals, ~100us) per kernel and reset at each boundary.
//
// In-kernel: R6's exact pipeline (passed, absmax 0.0625): x0/x1/x2 in
// 128 KB LDS, per-thread hreg/kacc in VGPRs, direct global->VGPR weight
// frags with register double-buffer, identical MFMA K-order.
// Across kernels: h crosses as fp32 in a PERMUTED layout (thread t of block
// b owns h_perm[(b*512+t)*32 .. +32) = 128 B contiguous, fully coalesced);
// x0 crosses as bf16 standard [m][n], staged back via the verified
// global_load_lds XOR-8 chunk pattern. 32 MB/step of boundary traffic.
// ===========================================================================

// L1: x1 = i8(tanh(x0 . W1^T + b1) * 127).  M=32, N=1024, K=512.
__device__ __forceinline__ void phase1(const bf16* __restrict__ W,
                                       const float* __restrict__ bias,
                                       const char* __restrict__ x0l,
                                       char* __restrict__ x1l) {
    const int tid = threadIdx.x;
    const int lane = tid & 63, w = tid >> 6;
    const int quad = lane >> 4, l16 = lane & 15;
    const int x7 = l16 & 7;

    floatx4 acc[2][8];
    const floatx4 zero = {0.f, 0.f, 0.f, 0.f};
#pragma unroll
    for (int mt = 0; mt < 2; ++mt)
#pragma unroll
        for (int nt = 0; nt < 8; ++nt) acc[mt][nt] = zero;

    const bf16* wp = W + (size_t)(w * 128 + l16) * 512 + quad * 8;
    short8 bA[8], bB[8];
#pragma unroll
    for (int nt = 0; nt < 8; ++nt) bA[nt] = *(const short8*)(wp + nt * 8192);

    for (int kt = 0; kt < 8; ++kt) {
#pragma unroll
        for (int nt = 0; nt < 8; ++nt)
            bB[nt] = *(const short8*)(wp + nt * 8192 + kt * 64 + 32);
        {
            const int c = kt * 8 + quad;          // kk = 0
            short8 af[2];
#pragma unroll
            for (int mt = 0; mt < 2; ++mt)
                af[mt] = *(const short8*)(x0l + (mt * 16 + l16) * 1024 + ((c ^ x7) << 4));
#pragma unroll
            for (int mt = 0; mt < 2; ++mt)
#pragma unroll
                for (int nt = 0; nt < 8; ++nt)
                    acc[mt][nt] = __builtin_amdgcn_mfma_f32_16x16x32_bf16(
                        af[mt], bA[nt], acc[mt][nt], 0, 0, 0);
        }
        if (kt + 1 < 8) {
#pragma unroll
            for (int nt = 0; nt < 8; ++nt)
                bA[nt] = *(const short8*)(wp + nt * 8192 + (kt + 1) * 64);
        }
        {
            const int c = kt * 8 + 4 + quad;      // kk = 1
            short8 af[2];
#pragma unroll
            for (int mt = 0; mt < 2; ++mt)
                af[mt] = *(const short8*)(x0l + (mt * 16 + l16) * 1024 + ((c ^ x7) << 4));
#pragma unroll
            for (int mt = 0; mt < 2; ++mt)
#pragma unroll
                for (int nt = 0; nt < 8; ++nt)
                    acc[mt][nt] = __builtin_amdgcn_mfma_f32_16x16x32_bf16(
                        af[mt], bB[nt], acc[mt][nt], 0, 0, 0);
        }
    }

    const int n0 = w * 128 + l16;
#pragma unroll
    for (int mt = 0; mt < 2; ++mt)
#pragma unroll
        for (int nt = 0; nt < 8; ++nt) {
            const int n = n0 + nt * 16;
            const float bb = bias[n];
#pragma unroll
            for (int i = 0; i < 4; ++i) {
                const int m = mt * 16 + quad * 4 + i;
                const float t = fast_tanh(acc[mt][nt][i] + bb);
                *(int8_t*)(x1l + m * 1024 + ((((n >> 4) ^ (m & 7)) << 4) | (n & 15))) =
                    (int8_t)__float2int_rn(t * 127.f);
            }
        }
}

// L2: x2 = bf16(tanh(acc*dq[n] + b2)), i8 core. M=32, N=1024, K=1024.
__device__ __forceinline__ void phase2(const int8_t* __restrict__ W,
                                       const float* __restrict__ dq,
                                       const float* __restrict__ bias,
                                       const char* __restrict__ x1l,
                                       char* __restrict__ x2l) {
    const int tid = threadIdx.x;
    const int lane = tid & 63, w = tid >> 6;
    const int quad = lane >> 4, l16 = lane & 15;
    const int x7 = l16 & 7;

    int4v acc[2][8];
    const int4v izero = {0, 0, 0, 0};
#pragma unroll
    for (int mt = 0; mt < 2; ++mt)
#pragma unroll
        for (int nt = 0; nt < 8; ++nt) acc[mt][nt] = izero;

    const int8_t* wp = W + (size_t)(w * 128 + l16) * 1024 + quad * 16;
    int4v bA[8], bB[8];
#pragma unroll
    for (int nt = 0; nt < 8; ++nt) bA[nt] = *(const int4v*)(wp + nt * 16384);

    for (int kt = 0; kt < 8; ++kt) {
#pragma unroll
        for (int nt = 0; nt < 8; ++nt)
            bB[nt] = *(const int4v*)(wp + nt * 16384 + kt * 128 + 64);
        {
            const int c = kt * 8 + quad;          // kk = 0
            int4v af[2];
#pragma unroll
            for (int mt = 0; mt < 2; ++mt)
                af[mt] = *(const int4v*)(x1l + (mt * 16 + l16) * 1024 + ((c ^ x7) << 4));
#pragma unroll
            for (int mt = 0; mt < 2; ++mt)
#pragma unroll
                for (int nt = 0; nt < 8; ++nt)
                    acc[mt][nt] = __builtin_amdgcn_mfma_i32_16x16x64_i8(
                        af[mt], bA[nt], acc[mt][nt], 0, 0, 0);
        }
        if (kt + 1 < 8) {
#pragma unroll
            for (int nt = 0; nt < 8; ++nt)
                bA[nt] = *(const int4v*)(wp + nt * 16384 + (kt + 1) * 128);
        }
        {
            const int c = kt * 8 + 4 + quad;      // kk = 1
            int4v af[2];
#pragma unroll
            for (int mt = 0; mt < 2; ++mt)
                af[mt] = *(const int4v*)(x1l + (mt * 16 + l16) * 1024 + ((c ^ x7) << 4));
#pragma unroll
            for (int mt = 0; mt < 2; ++mt)
#pragma unroll
                for (int nt = 0; nt < 8; ++nt)
                    acc[mt][nt] = __builtin_amdgcn_mfma_i32_16x16x64_i8(
                        af[mt], bB[nt], acc[mt][nt], 0, 0, 0);
        }
    }

    const int n0 = w * 128 + l16;
#pragma unroll
    for (int mt = 0; mt < 2; ++mt)
#pragma unroll
        for (int nt = 0; nt < 8; ++nt) {
            const int n = n0 + nt * 16;
            const float bb = bias[n];
            const float dqn = dq[n];
#pragma unroll
            for (int i = 0; i < 4; ++i) {
                const int m = mt * 16 + quad * 4 + i;
                *(bf16*)(x2l + m * 2048 + ((((n >> 3) ^ (m & 7)) << 4) | ((n & 7) * 2))) =
                    __float2bfloat16(fast_tanh((float)acc[mt][nt][i] * dqn + bb));
            }
        }
}

__global__ void __launch_bounds__(512, 2)
ode_step(float* __restrict__ h_perm, float* __restrict__ h_fin,
         bf16* __restrict__ x0g,
         const bf16* __restrict__ W1b, const float* __restrict__ b1,
         const int8_t* __restrict__ W2i, const float* __restrict__ dqv,
         const float* __restrict__ b2,
         const bf16* __restrict__ W3b, const float* __restrict__ b3,
         const float* __restrict__ tmid, const float* __restrict__ tend,
         int last) {
    __shared__ alignas(16) char smem[131072];
    char* x0l = smem;             // 32 KB bf16 [32][512]  (XOR-8 16B-chunk swz)
    char* x1l = smem + 32768;     // 32 KB i8  [32][1024]
    char* x2l = smem + 65536;     // 64 KB bf16[32][1024]

    const int row0 = blockIdx.x * 32;          // 256 blocks x 32 rows
    const int tid = threadIdx.x;
    const int lane = tid & 63, w = tid >> 6;
    const int quad = lane >> 4, l16 = lane & 15;
    const int x7 = l16 & 7;
    const float dt = 0.1f;

    // ---- stage x0 global -> LDS (verified pattern: linear dest, XOR src) ----
#pragma unroll
    for (int jj = 0; jj < 4; ++jj) {           // 2048 chunks: 32 rows x 64
        const int q = tid + jj * 512;
        const int r = q >> 6, p = q & 63, sg = p ^ (r & 7);
        load_lds16(x0g + (size_t)(row0 + r) * 512 + sg * 8, x0l + q * 16);
    }

    // ---- per-thread RK4 state, coalesced load (128 B contiguous/thread) ----
    const size_t hbase = ((size_t)blockIdx.x * 512 + tid) * 32;
    float hreg[32], kacc[32];
#pragma unroll
    for (int j = 0; j < 32; ++j) hreg[j] = h_perm[hbase + j];
#pragma unroll
    for (int j = 0; j < 32; ++j) kacc[j] = 0.f;

    for (int e = 0; e < 4; ++e) {
        __syncthreads();                    // staging done / x0 writes visible
        phase1(W1b, b1, x0l, x1l);
        __syncthreads();                    // x1 writes visible
        phase2(W2i, dqv, b2, x1l, x2l);
        __syncthreads();                    // x2 writes visible

        // ---- L3: M=32, N=512, K=1024, A = x2_lds, reg-dbuf W ----
        floatx4 acc3[2][4];
        const floatx4 zero = {0.f, 0.f, 0.f, 0.f};
#pragma unroll
        for (int mt = 0; mt < 2; ++mt)
#pragma unroll
            for (int nt = 0; nt < 4; ++nt) acc3[mt][nt] = zero;

        const bf16* wp3 = W3b + (size_t)(w * 64 + l16) * 1024 + quad * 8;
        short8 cA[4], cB[4];
#pragma unroll
        for (int nt = 0; nt < 4; ++nt) cA[nt] = *(const short8*)(wp3 + nt * 16384);

        for (int kt = 0; kt < 16; ++kt) {
#pragma unroll
            for (int nt = 0; nt < 4; ++nt)
                cB[nt] = *(const short8*)(wp3 + nt * 16384 + kt * 64 + 32);
            {
                const int c = kt * 8 + quad;          // kk = 0
                short8 af[2];
#pragma unroll
                for (int mt = 0; mt < 2; ++mt)
                    af[mt] = *(const short8*)(x2l + (mt * 16 + l16) * 2048 +
                                              ((c ^ x7) << 4));
#pragma unroll
                for (int mt = 0; mt < 2; ++mt)
#pragma unroll
                    for (int nt = 0; nt < 4; ++nt)
                        acc3[mt][nt] = __builtin_amdgcn_mfma_f32_16x16x32_bf16(
                            af[mt], cA[nt], acc3[mt][nt], 0, 0, 0);
            }
            if (kt + 1 < 16) {
#pragma unroll
                for (int nt = 0; nt < 4; ++nt)
                    cA[nt] = *(const short8*)(wp3 + nt * 16384 + (kt + 1) * 64);
            }
            {
                const int c = kt * 8 + 4 + quad;      // kk = 1
                short8 af[2];
#pragma unroll
                for (int mt = 0; mt < 2; ++mt)
                    af[mt] = *(const short8*)(x2l + (mt * 16 + l16) * 2048 +
                                              ((c ^ x7) << 4));
#pragma unroll
                for (int mt = 0; mt < 2; ++mt)
#pragma unroll
                    for (int nt = 0; nt < 4; ++nt)
                        acc3[mt][nt] = __builtin_amdgcn_mfma_f32_16x16x32_bf16(
                            af[mt], cB[nt], acc3[mt][nt], 0, 0, 0);
            }
        }
        __syncthreads();                    // x2 reads done before x0 overwrite

        // ---- RK4 epilogue (register kacc/h) ----
        const float* te = (e <= 1) ? tmid : tend;
#pragma unroll
        for (int mt = 0; mt < 2; ++mt)
#pragma unroll
            for (int nt = 0; nt < 4; ++nt) {
                const int n = w * 64 + nt * 16 + l16;
                const float bb = b3[n];
                const float tv = te[n];
#pragma unroll
                for (int i = 0; i < 4; ++i) {
                    const int j = (mt * 4 + nt) * 4 + i;
                    const int m = mt * 16 + quad * 4 + i;
                    const float kv = acc3[mt][nt][i] + bb;
                    float xnew;
                    if (e == 0) {
                        kacc[j] = kv;
                        const float hbf = __bfloat162float(__float2bfloat16(hreg[j]));
                        xnew = hbf + 0.05f * kv + tv;
                    } else if (e == 1) {
                        kacc[j] += 2.f * kv;
                        const float hbf = __bfloat162float(__float2bfloat16(hreg[j]));
                        xnew = hbf + 0.05f * kv + tv;
                    } else if (e == 2) {
                        kacc[j] += 2.f * kv;
                        const float hbf = __bfloat162float(__float2bfloat16(hreg[j]));
                        xnew = hbf + 0.1f * kv + tv;
                    } else {
                        const float hn = hreg[j] + (dt / 6.f) * (kacc[j] + kv);
                        hreg[j] = hn;
                        if (last) {
                            h_fin[(size_t)(row0 + m) * 512 + n] = hn;
                        } else {
                            // x0 for next step's kernel + persistent h
                            x0g[(size_t)(row0 + m) * 512 + n] =
                                __float2bfloat16(hn + tv);
                        }
                        continue;
                    }
                    *(bf16*)(x0l + m * 1024 +
                             ((((n >> 3) ^ (m & 7)) << 4) | ((n & 7) * 2))) =
                        __float2bfloat16(xnew);
                }
            }
    }

    // persist h for the next step kernel (coalesced)
    if (!last) {
#pragma unroll
        for (int j = 0; j < 32; ++j) h_perm[hbase + j] = hreg[j];
    }
}

// ===========================================================================
// Prep kernels.
// ===========================================================================

__global__ void f2b_kern(const float* __restrict__ src, bf16* __restrict__ dst, int n) {
    const int i = blockIdx.x * blockDim.x + threadIdx.x;
    if (i < n) dst[i] = __float2bfloat16(src[i]);
}

// Per-row i8 quantization of W2 (N=1024 rows, K=1024): row n scaled by
// 127/rowmax_n (clamped), dq[n] = rowmax_n/127^2 (includes x1's /127).
__global__ void quantW2_row(const float* __restrict__ W, int K,
                            int8_t* __restrict__ out, float* __restrict__ dq) {
    __shared__ float red[256];
    const int row = blockIdx.x, tid = threadIdx.x;
    const float* src = W + (size_t)row * K;
    float m = 0.f;
    for (int k = tid; k < K; k += 256) m = fmaxf(m, fabsf(src[k]));
    red[tid] = m;
    __syncthreads();
    for (int s = 128; s > 0; s >>= 1) {
        if (tid < s) red[tid] = fmaxf(red[tid], red[tid + s]);
        __syncthreads();
    }
    const float rmax = fmaxf(red[0], 1e-8f);
    const float sc = 127.f / rmax;
    int8_t* dst = out + (size_t)row * K;
    for (int k = tid; k < K; k += 256) {
        int v = __float2int_rn(src[k] * sc);
        v = v > 127 ? 127 : (v < -127 ? -127 : v);
        dst[k] = (int8_t)v;
    }
    if (tid == 0) dq[row] = rmax / (127.f * 127.f);
}

// temb[j][n] = (j*dt/2)*Wt[n] + bt[n], j = 0..20
__global__ void temb_kern(const float* __restrict__ Wt, const float* __restrict__ bt,
                          float* __restrict__ temb, float half_dt, int total) {
    const int i = blockIdx.x * blockDim.x + threadIdx.x;
    if (i < total) {
        const int j = i >> 9, n = i & 511;
        temb[i] = (j * half_dt) * Wt[n] + bt[n];
    }
}

// x0g = bf16(h + temb0) (standard layout), h_perm = h gathered into the
// per-thread 32-element contiguous layout used by ode_step.
__global__ void prep2_kern(const float* __restrict__ h, const float* __restrict__ temb0,
                           bf16* __restrict__ x0g, float* __restrict__ h_perm) {
    const int row0 = blockIdx.x * 32;
    const int tid = threadIdx.x;
    for (int idx = tid; idx < 32 * 512; idx += 512) {
        const int m = idx >> 9, e = idx & 511;
        const size_t gi = (size_t)(row0 + m) * 512 + e;
        x0g[gi] = __float2bfloat16(h[gi] + temb0[e]);
    }
    const int lane = tid & 63, w = tid >> 6;
    const int quad = lane >> 4, l16 = lane & 15;
    const size_t hbase = ((size_t)blockIdx.x * 512 + tid) * 32;
#pragma unroll
    for (int mt = 0; mt < 2; ++mt)
#pragma unroll
        for (int nt = 0; nt < 4; ++nt)
#pragma unroll
            for (int i = 0; i < 4; ++i)
                h_perm[hbase + (mt * 4 + nt) * 4 + i] =
                    h[(size_t)(row0 + mt * 16 + quad * 4 + i) * 512 +
                      (w * 64 + nt * 16 + l16)];
}

extern "C" void kernel_launch(void* const* d_in, const int* in_sizes, int n_in,
                              void* d_out, int out_size, void* d_ws, size_t ws_size,
                              hipStream_t stream) {
    const float* h_in = (const float*)d_in[0];
    const float* W1 = (const float*)d_in[1];
    const float* b1 = (const float*)d_in[2];
    const float* W2 = (const float*)d_in[3];
    const float* b2 = (const float*)d_in[4];
    const float* W3 = (const float*)d_in[5];
    const float* b3 = (const float*)d_in[6];
    const float* Wt = (const float*)d_in[7];
    const float* bt = (const float*)d_in[8];
    const int B = 8192, H = 512, H2 = 1024, NS = 10;
    const float dt = 0.1f;

    char* ws = (char*)d_ws;
    auto alloc = [&](size_t bytes) {
        char* p = ws;
        ws += (bytes + 255) & ~(size_t)255;
        return p;
    };
    bf16* W1b = (bf16*)alloc((size_t)H2 * H * 2);
    int8_t* W2i = (int8_t*)alloc((size_t)H2 * H2);      // i8, per-row scaled
    float* dqv  = (float*)alloc((size_t)H2 * 4);        // per-row dequant
    bf16* W3b = (bf16*)alloc((size_t)H * H2 * 2);
    float* temb = (float*)alloc((size_t)21 * H * 4);
    bf16* x0g  = (bf16*)alloc((size_t)B * H * 2);       // x0 across step kernels
    float* h_perm = (float*)alloc((size_t)B * H * 4);   // h, permuted coalesced
    float* h_fin = (float*)d_out;                       // final h (fp32)

    {
        int n = H2 * H;
        f2b_kern<<<(n + 255) / 256, 256, 0, stream>>>(W1, W1b, n);
        quantW2_row<<<H2, 256, 0, stream>>>(W2, H2, W2i, dqv);
        n = H * H2;
        f2b_kern<<<(n + 255) / 256, 256, 0, stream>>>(W3, W3b, n);
        const int total = 21 * H;
        temb_kern<<<(total + 255) / 256, 256, 0, stream>>>(Wt, bt, temb, dt * 0.5f, total);
    }
    prep2_kern<<<dim3(256), dim3(512), 0, stream>>>(h_in, temb, x0g, h_perm);

    // 10 per-step kernels: drift bounded to one RK4 step, state in registers.
    for (int s = 0; s < NS; ++s) {
        const float* tmid = temb + (size_t)(2 * s + 1) * H;
        const float* tend = temb + (size_t)(2 * s + 2) * H;
        ode_step<<<dim3(256), dim3(512), 0, stream>>>(
            h_perm, h_fin, x0g, W1b, b1, W2i, dqv, b2, W3b, b3,
            tmid, tend, (s == NS - 1) ? 1 : 0);
    }
}

// Round 8
// 2103.432 us; speedup vs baseline: 9.8102x; 9.8102x over previous
//
#include <hip/hip_runtime.h>
#include <hip/hip_bf16.h>
#include <math.h>
#include <stdint.h>

using bf16 = __hip_bfloat16;
typedef __attribute__((ext_vector_type(8))) short short8;   // 8 bf16 (MFMA A/B frag)
typedef __attribute__((ext_vector_type(4))) float floatx4;  // MFMA C/D frag (f32)
typedef __attribute__((ext_vector_type(4))) int int4v;      // i8 K=64 frag / i32 acc

typedef const __attribute__((address_space(1))) void* gptr_t;
typedef __attribute__((address_space(3))) void* lptr_t;

__device__ __forceinline__ void load_lds16(const void* g, void* l) {
    __builtin_amdgcn_global_load_lds((gptr_t)(uintptr_t)g, (lptr_t)(uintptr_t)l, 16, 0, 0);
}

// wait until at most N vector-memory ops outstanding. gfx9 vmcnt 6 bits:
// lo[3:0]=bits3:0, hi[5:4]=bits15:14; lgkm/exp left at max (no wait).
#define WAIT_VM(n) __builtin_amdgcn_s_waitcnt(0x0F70 | ((n) & 15) | (((n) >> 4) << 14))

// tanh(x) = 1 - 2/(exp(2x)+1)
__device__ __forceinline__ float fast_tanh(float x) {
    float e = __expf(2.f * x);
    return 1.f - 2.f / (e + 1.f);
}

// ---------------------------------------------------------------------------
// R8 = R1 restored (verified 2186us; the tile-parallel per-phase structure is
// the only one that keeps weights L2-hot: each block reads a 1/8 weight slice
// and M-neighbors reuse it within microseconds; R4-R7 proved every
// all-weights-per-block fusion thrashes the per-XCD L2) + ONE change:
// L3 switched to the VERIFIED i8 core. x2 = tanh(.) in (-1,1) -> fixed x127
// i8 (same representation as the verified x1 path); W3 per-row i8 quant like
// W2; i8 accum is exact integer so no K-order sensitivity. L3 MFMA + LDS
// halves; x2 traffic halves (16->8 MB/eval); L2 writes halve.
// ---------------------------------------------------------------------------

// L1: x1i = i8(tanh(A.W1^T + b1)*127), bf16 core. 128x128, dbuf, 2 blk/CU.
__global__ void __launch_bounds__(256, 2)
gemm_tanh4(const bf16* __restrict__ A, const bf16* __restrict__ W,
           const float* __restrict__ bias, int8_t* __restrict__ out,
           int K, int N) {
    constexpr int MT = 4, NT = 4;
    __shared__ alignas(16) bf16 lA[2][128 * 64];
    __shared__ alignas(16) bf16 lB[2][128 * 64];

    const int b   = blockIdx.x + gridDim.x * blockIdx.y;   // grid (8, 64)
    const int xcd = b & 7, j = b >> 3;
    const int bx  = j & 7;
    const int by  = xcd + 8 * (j >> 3);

    const int tid  = threadIdx.x;
    const int lane = tid & 63;
    const int w    = tid >> 6;
    const int wr   = w >> 1, wc = w & 1;
    const int quad = lane >> 4, l16 = lane & 15;
    const int brow = by * 128;
    const int bcol = bx * 128;

    const bf16* gA[4]; const bf16* gW[4]; int lq[4];
#pragma unroll
    for (int jj = 0; jj < 4; ++jj) {
        const int q = tid + jj * 256;
        const int r = q >> 3, s = (q & 7) ^ (r & 7);
        gA[jj] = A + (size_t)(brow + r) * K + s * 8;
        gW[jj] = W + (size_t)(bcol + r) * K + s * 8;
        lq[jj] = q * 8;
    }

    floatx4 acc[MT][NT];
    const floatx4 zero = {0.f, 0.f, 0.f, 0.f};
#pragma unroll
    for (int mt = 0; mt < MT; ++mt)
#pragma unroll
        for (int nt = 0; nt < NT; ++nt) acc[mt][nt] = zero;

    const int arow0 = wr * 64 + l16;
    const int brow0 = wc * 64 + l16;
    const int x7 = l16 & 7;

    const int nIter = K / 64;
#pragma unroll
    for (int jj = 0; jj < 4; ++jj) load_lds16(gA[jj], &lA[0][0] + lq[jj]);
#pragma unroll
    for (int jj = 0; jj < 4; ++jj) load_lds16(gW[jj], &lB[0][0] + lq[jj]);

    for (int kt = 0; kt < nIter; ++kt) {
        const int cur = kt & 1;
        if (kt + 1 < nIter) {
#pragma unroll
            for (int jj = 0; jj < 4; ++jj)
                load_lds16(gA[jj] + (kt + 1) * 64, &lA[cur ^ 1][0] + lq[jj]);
#pragma unroll
            for (int jj = 0; jj < 4; ++jj)
                load_lds16(gW[jj] + (kt + 1) * 64, &lB[cur ^ 1][0] + lq[jj]);
            WAIT_VM(8);
        } else {
            WAIT_VM(0);
        }
        __builtin_amdgcn_s_barrier();

#pragma unroll
        for (int kk = 0; kk < 2; ++kk) {
            const int sw = ((kk * 4 + quad) ^ x7) * 8;
            short8 af[MT], bfr[NT];
#pragma unroll
            for (int mt = 0; mt < MT; ++mt)
                af[mt] = *(const short8*)(&lA[cur][0] + (arow0 + mt * 16) * 64 + sw);
#pragma unroll
            for (int nt = 0; nt < NT; ++nt)
                bfr[nt] = *(const short8*)(&lB[cur][0] + (brow0 + nt * 16) * 64 + sw);
#pragma unroll
            for (int mt = 0; mt < MT; ++mt)
#pragma unroll
                for (int nt = 0; nt < NT; ++nt)
                    acc[mt][nt] = __builtin_amdgcn_mfma_f32_16x16x32_bf16(
                        af[mt], bfr[nt], acc[mt][nt], 0, 0, 0);
        }
        __builtin_amdgcn_s_barrier();
    }

    const int m0 = brow + wr * 64 + quad * 4;
    const int n0 = bcol + wc * 64 + l16;
#pragma unroll
    for (int mt = 0; mt < MT; ++mt)
#pragma unroll
        for (int nt = 0; nt < NT; ++nt) {
            const int n = n0 + nt * 16;
            const float bb = bias[n];
#pragma unroll
            for (int i = 0; i < 4; ++i) {
                const int m = m0 + mt * 16 + i;
                const float t = fast_tanh(acc[mt][nt][i] + bb);
                out[(size_t)m * N + n] = (int8_t)__float2int_rn(t * 127.f);
            }
        }
}

// L2: x2i = i8(tanh(acc*dq[n] + b2)*127), i8 core. 128x128, dbuf, 2 blk/CU.
__global__ void __launch_bounds__(256, 2)
gemm_tanh_i8(const int8_t* __restrict__ A, const int8_t* __restrict__ W,
             const float* __restrict__ dq, const float* __restrict__ bias,
             int8_t* __restrict__ out, int K, int N) {
    constexpr int MT = 4, NT = 4;
    __shared__ alignas(16) int8_t lA[2][128 * 128];
    __shared__ alignas(16) int8_t lB[2][128 * 128];

    const int b   = blockIdx.x + gridDim.x * blockIdx.y;   // grid (8, 64)
    const int xcd = b & 7, j = b >> 3;
    const int bx  = j & 7;
    const int by  = xcd + 8 * (j >> 3);

    const int tid  = threadIdx.x;
    const int lane = tid & 63;
    const int w    = tid >> 6;
    const int wr   = w >> 1, wc = w & 1;
    const int quad = lane >> 4, l16 = lane & 15;
    const int brow = by * 128;
    const int bcol = bx * 128;

    const int8_t* gA[4]; const int8_t* gW[4]; int lq[4];
#pragma unroll
    for (int jj = 0; jj < 4; ++jj) {
        const int q = tid + jj * 256;
        const int r = q >> 3, s = (q & 7) ^ (r & 7);
        gA[jj] = A + (size_t)(brow + r) * K + s * 16;
        gW[jj] = W + (size_t)(bcol + r) * K + s * 16;
        lq[jj] = q * 16;
    }

    int4v acc[MT][NT];
    const int4v izero = {0, 0, 0, 0};
#pragma unroll
    for (int mt = 0; mt < MT; ++mt)
#pragma unroll
        for (int nt = 0; nt < NT; ++nt) acc[mt][nt] = izero;

    const int arow0 = wr * 64 + l16;
    const int brow0 = wc * 64 + l16;
    const int x7 = l16 & 7;

    const int nIter = K / 128;   // 8 for K=1024
#pragma unroll
    for (int jj = 0; jj < 4; ++jj) load_lds16(gA[jj], &lA[0][0] + lq[jj]);
#pragma unroll
    for (int jj = 0; jj < 4; ++jj) load_lds16(gW[jj], &lB[0][0] + lq[jj]);

    for (int kt = 0; kt < nIter; ++kt) {
        const int cur = kt & 1;
        if (kt + 1 < nIter) {
#pragma unroll
            for (int jj = 0; jj < 4; ++jj)
                load_lds16(gA[jj] + (kt + 1) * 128, &lA[cur ^ 1][0] + lq[jj]);
#pragma unroll
            for (int jj = 0; jj < 4; ++jj)
                load_lds16(gW[jj] + (kt + 1) * 128, &lB[cur ^ 1][0] + lq[jj]);
            WAIT_VM(8);
        } else {
            WAIT_VM(0);
        }
        __builtin_amdgcn_s_barrier();

#pragma unroll
        for (int kk = 0; kk < 2; ++kk) {
            const int sw = ((kk * 4 + quad) ^ x7) * 16;
            int4v af[MT], bfr[NT];
#pragma unroll
            for (int mt = 0; mt < MT; ++mt)
                af[mt] = *(const int4v*)(&lA[cur][(arow0 + mt * 16) * 128 + sw]);
#pragma unroll
            for (int nt = 0; nt < NT; ++nt)
                bfr[nt] = *(const int4v*)(&lB[cur][(brow0 + nt * 16) * 128 + sw]);
#pragma unroll
            for (int mt = 0; mt < MT; ++mt)
#pragma unroll
                for (int nt = 0; nt < NT; ++nt)
                    acc[mt][nt] = __builtin_amdgcn_mfma_i32_16x16x64_i8(
                        af[mt], bfr[nt], acc[mt][nt], 0, 0, 0);
        }
        __builtin_amdgcn_s_barrier();
    }

    const int m0 = brow + wr * 64 + quad * 4;
    const int n0 = bcol + wc * 64 + l16;
#pragma unroll
    for (int mt = 0; mt < MT; ++mt)
#pragma unroll
        for (int nt = 0; nt < NT; ++nt) {
            const int n = n0 + nt * 16;
            const float bb = bias[n];
            const float dqn = dq[n];
#pragma unroll
            for (int i = 0; i < 4; ++i) {
                const int m = m0 + mt * 16 + i;
                const float t = fast_tanh((float)acc[mt][nt][i] * dqn + bb);
                out[(size_t)m * N + n] = (int8_t)__float2int_rn(t * 127.f);
            }
        }
}

// L3: RK4-fused i8 GEMM. A = x2i (x2*127), W = per-row i8 W3, K=1024, N=512.
// 128x64 tile (MT=4, NT=2), dbuf 48 KB, 2 blk/CU. kv = acc*dq3[n] + b3[n].
// mode 0 (k1):   kacc = kv;     x0 = bf16(hb + alpha*kv + te)
// mode 1 (k2/3): kacc += 2*kv;  x0 = bf16(hb + alpha*kv + te)
// mode 2 (k4):   hn = h_f32 + dt6*(kacc + kv); h_out=hn; hb_out=bf16(hn);
//                if (x0_out) x0 = bf16(hn + te)
__global__ void __launch_bounds__(256, 2)
gemm_k(const int8_t* __restrict__ A, const int8_t* __restrict__ W,
       const float* __restrict__ dq, const float* __restrict__ bias, int K,
       bf16* __restrict__ kacc, const bf16* __restrict__ hb_src,
       const float* __restrict__ h_src, float* __restrict__ h_out,
       bf16* __restrict__ hb_out, bf16* __restrict__ x0_out,
       const float* __restrict__ temb, float alpha, float dt6, int mode) {
    constexpr int MT = 4, NT = 2;
    __shared__ alignas(16) int8_t lA[2][128 * 128];   // 2 x 16 KB
    __shared__ alignas(16) int8_t lB[2][64 * 128];    // 2 x  8 KB

    const int b   = blockIdx.x + gridDim.x * blockIdx.y;   // grid (8, 64)
    const int xcd = b & 7, j = b >> 3;
    const int bx  = j & 7;                                  // 8 N-tiles
    const int by  = xcd + 8 * (j >> 3);                     // 64 M-tiles

    const int tid  = threadIdx.x;
    const int lane = tid & 63;
    const int w    = tid >> 6;
    const int wr   = w >> 1, wc = w & 1;
    const int quad = lane >> 4, l16 = lane & 15;
    const int brow = by * 128;
    const int bcol = bx * 64;

    // staging: A = 128 rows x 8 chunks of 16B (1024 = 4/thr); B = 64 x 8
    // (512 = 2/thr); XOR-8 swizzle (slot p of row r holds chunk p^(r&7)).
    const int8_t* gA[4]; int lqA[4];
    const int8_t* gW[2]; int lqB[2];
#pragma unroll
    for (int jj = 0; jj < 4; ++jj) {
        const int q = tid + jj * 256;
        const int r = q >> 3, s = (q & 7) ^ (r & 7);
        gA[jj]  = A + (size_t)(brow + r) * K + s * 16;
        lqA[jj] = q * 16;
    }
#pragma unroll
    for (int jj = 0; jj < 2; ++jj) {
        const int q = tid + jj * 256;
        const int r = q >> 3, s = (q & 7) ^ (r & 7);
        gW[jj]  = W + (size_t)(bcol + r) * K + s * 16;
        lqB[jj] = q * 16;
    }

    int4v acc[MT][NT];
    const int4v izero = {0, 0, 0, 0};
#pragma unroll
    for (int mt = 0; mt < MT; ++mt)
#pragma unroll
        for (int nt = 0; nt < NT; ++nt) acc[mt][nt] = izero;

    const int arow0 = wr * 64 + l16;
    const int brow0 = wc * 32 + l16;
    const int x7 = l16 & 7;

    const int nIter = K / 128;   // 8 for K=1024
#pragma unroll
    for (int jj = 0; jj < 4; ++jj) load_lds16(gA[jj], &lA[0][0] + lqA[jj]);
#pragma unroll
    for (int jj = 0; jj < 2; ++jj) load_lds16(gW[jj], &lB[0][0] + lqB[jj]);

    for (int kt = 0; kt < nIter; ++kt) {
        const int cur = kt & 1;
        if (kt + 1 < nIter) {
#pragma unroll
            for (int jj = 0; jj < 4; ++jj)
                load_lds16(gA[jj] + (kt + 1) * 128, &lA[cur ^ 1][0] + lqA[jj]);
#pragma unroll
            for (int jj = 0; jj < 2; ++jj)
                load_lds16(gW[jj] + (kt + 1) * 128, &lB[cur ^ 1][0] + lqB[jj]);
            WAIT_VM(6);
        } else {
            WAIT_VM(0);
        }
        __builtin_amdgcn_s_barrier();

        // two K=64 i8 MFMA groups per staged k128
#pragma unroll
        for (int kk = 0; kk < 2; ++kk) {
            const int sw = ((kk * 4 + quad) ^ x7) * 16;
            int4v af[MT], bfr[NT];
#pragma unroll
            for (int mt = 0; mt < MT; ++mt)
                af[mt] = *(const int4v*)(&lA[cur][(arow0 + mt * 16) * 128 + sw]);
#pragma unroll
            for (int nt = 0; nt < NT; ++nt)
                bfr[nt] = *(const int4v*)(&lB[cur][(brow0 + nt * 16) * 128 + sw]);
#pragma unroll
            for (int mt = 0; mt < MT; ++mt)
#pragma unroll
                for (int nt = 0; nt < NT; ++nt)
                    acc[mt][nt] = __builtin_amdgcn_mfma_i32_16x16x64_i8(
                        af[mt], bfr[nt], acc[mt][nt], 0, 0, 0);
        }
        __builtin_amdgcn_s_barrier();
    }

    const int m0 = brow + wr * 64 + quad * 4;
    const int n0 = bcol + wc * 32 + l16;
#pragma unroll
    for (int mt = 0; mt < MT; ++mt)
#pragma unroll
        for (int nt = 0; nt < NT; ++nt) {
            const int n = n0 + nt * 16;
            const float bb = bias[n];
            const float dqn = dq[n];
            const float te = temb[n];
#pragma unroll
            for (int i = 0; i < 4; ++i) {
                const int m = m0 + mt * 16 + i;
                const size_t idx = (size_t)m * 512 + n;
                const float kv = (float)acc[mt][nt][i] * dqn + bb;
                if (mode == 0) {
                    kacc[idx] = __float2bfloat16(kv);
                    x0_out[idx] = __float2bfloat16(
                        __bfloat162float(hb_src[idx]) + alpha * kv + te);
                } else if (mode == 1) {
                    kacc[idx] = __float2bfloat16(__bfloat162float(kacc[idx]) + 2.f * kv);
                    x0_out[idx] = __float2bfloat16(
                        __bfloat162float(hb_src[idx]) + alpha * kv + te);
                } else {
                    const float hn = h_src[idx] + dt6 * (__bfloat162float(kacc[idx]) + kv);
                    h_out[idx] = hn;
                    hb_out[idx] = __float2bfloat16(hn);
                    if (x0_out) x0_out[idx] = __float2bfloat16(hn + te);
                }
            }
        }
}

__global__ void f2b_kern(const float* __restrict__ src, bf16* __restrict__ dst, int n) {
    const int i = blockIdx.x * blockDim.x + threadIdx.x;
    if (i < n) dst[i] = __float2bfloat16(src[i]);
}

// Per-row i8 quantization (rows = gridDim.x, length K): row n scaled by
// 127/rowmax_n (clamped), dq[n] = rowmax_n/127^2 (includes A's /127).
__global__ void quantW_row(const float* __restrict__ W, int K,
                           int8_t* __restrict__ out, float* __restrict__ dq) {
    __shared__ float red[256];
    const int row = blockIdx.x, tid = threadIdx.x;
    const float* src = W + (size_t)row * K;
    float m = 0.f;
    for (int k = tid; k < K; k += 256) m = fmaxf(m, fabsf(src[k]));
    red[tid] = m;
    __syncthreads();
    for (int s = 128; s > 0; s >>= 1) {
        if (tid < s) red[tid] = fmaxf(red[tid], red[tid + s]);
        __syncthreads();
    }
    const float rmax = fmaxf(red[0], 1e-8f);
    const float sc = 127.f / rmax;
    int8_t* dst = out + (size_t)row * K;
    for (int k = tid; k < K; k += 256) {
        int v = __float2int_rn(src[k] * sc);
        v = v > 127 ? 127 : (v < -127 ? -127 : v);
        dst[k] = (int8_t)v;
    }
    if (tid == 0) dq[row] = rmax / (127.f * 127.f);
}

// temb[j][n] = (j*dt/2)*Wt[n] + bt[n], j = 0..20
__global__ void temb_kern(const float* __restrict__ Wt, const float* __restrict__ bt,
                          float* __restrict__ temb, float half_dt, int total) {
    const int i = blockIdx.x * blockDim.x + threadIdx.x;
    if (i < total) {
        const int j = i >> 9, n = i & 511;
        temb[i] = (j * half_dt) * Wt[n] + bt[n];
    }
}

__global__ void prep_kern(const float* __restrict__ h, const float* __restrict__ temb0,
                          bf16* __restrict__ x0, bf16* __restrict__ hb, int total) {
    const int i = blockIdx.x * blockDim.x + threadIdx.x;
    if (i < total) {
        const float hv = h[i];
        x0[i] = __float2bfloat16(hv + temb0[i & 511]);
        hb[i] = __float2bfloat16(hv);
    }
}

extern "C" void kernel_launch(void* const* d_in, const int* in_sizes, int n_in,
                              void* d_out, int out_size, void* d_ws, size_t ws_size,
                              hipStream_t stream) {
    const float* h_in = (const float*)d_in[0];
    const float* W1 = (const float*)d_in[1];
    const float* b1 = (const float*)d_in[2];
    const float* W2 = (const float*)d_in[3];
    const float* b2 = (const float*)d_in[4];
    const float* W3 = (const float*)d_in[5];
    const float* b3 = (const float*)d_in[6];
    const float* Wt = (const float*)d_in[7];
    const float* bt = (const float*)d_in[8];
    // n_steps (d_in[9]) is a fixed Python scalar = 10.
    const int B = 8192, H = 512, H2 = 1024, NS = 10;
    const float dt = 1.f / NS;

    char* ws = (char*)d_ws;
    auto alloc = [&](size_t bytes) {
        char* p = ws;
        ws += (bytes + 255) & ~(size_t)255;
        return p;
    };
    bf16* W1b = (bf16*)alloc((size_t)H2 * H * 2);
    int8_t* W2i = (int8_t*)alloc((size_t)H2 * H2);      // i8, per-row scaled
    float* dq2  = (float*)alloc((size_t)H2 * 4);        // per-row dequant W2
    int8_t* W3i = (int8_t*)alloc((size_t)H * H2);       // i8, per-row scaled
    float* dq3  = (float*)alloc((size_t)H * 4);         // per-row dequant W3
    bf16* x0b = (bf16*)alloc((size_t)B * H * 2);
    int8_t* x1i = (int8_t*)alloc((size_t)B * H2);       // i8 tanh1 * 127
    int8_t* x2i = (int8_t*)alloc((size_t)B * H2);       // i8 tanh2 * 127
    bf16* kacc = (bf16*)alloc((size_t)B * H * 2);
    bf16* hb   = (bf16*)alloc((size_t)B * H * 2);
    float* temb = (float*)alloc((size_t)21 * H * 4);
    float* hbuf = (float*)d_out;  // h ping-pongs through d_out (fp32)

    {
        int n = H2 * H;
        f2b_kern<<<(n + 255) / 256, 256, 0, stream>>>(W1, W1b, n);
        quantW_row<<<H2, 256, 0, stream>>>(W2, H2, W2i, dq2);
        quantW_row<<<H, 256, 0, stream>>>(W3, H2, W3i, dq3);
    }
    {
        const int total = 21 * H;
        temb_kern<<<(total + 255) / 256, 256, 0, stream>>>(Wt, bt, temb, dt * 0.5f, total);
    }
    {
        const int total = B * H;
        prep_kern<<<(total + 255) / 256, 256, 0, stream>>>(h_in, temb, x0b, hb, total);
    }

    const dim3 blk256(256);
    const dim3 g12(H2 / 128, B / 128);  // 8 x 64 = 512 blocks (2/CU)
    const dim3 g3(H / 64, B / 128);     // 8 x 64 = 512 blocks (2/CU), 128x64

    for (int s = 0; s < NS; ++s) {
        const float* hs = (s == 0) ? h_in : hbuf;
        const float* tmid = temb + (size_t)(2 * s + 1) * H;
        const float* tend = temb + (size_t)(2 * s + 2) * H;
        for (int e = 0; e < 4; ++e) {
            gemm_tanh4<<<g12, blk256, 0, stream>>>(x0b, W1b, b1, x1i, H, H2);
            gemm_tanh_i8<<<g12, blk256, 0, stream>>>(x1i, W2i, dq2, b2, x2i, H2, H2);
            if (e == 0)
                gemm_k<<<g3, blk256, 0, stream>>>(x2i, W3i, dq3, b3, H2, kacc, hb, hs,
                                                  nullptr, nullptr, x0b, tmid,
                                                  dt * 0.5f, 0.f, 0);
            else if (e == 1)
                gemm_k<<<g3, blk256, 0, stream>>>(x2i, W3i, dq3, b3, H2, kacc, hb, hs,
                                                  nullptr, nullptr, x0b, tmid,
                                                  dt * 0.5f, 0.f, 1);
            else if (e == 2)
                gemm_k<<<g3, blk256, 0, stream>>>(x2i, W3i, dq3, b3, H2, kacc, hb, hs,
                                                  nullptr, nullptr, x0b, tend,
                                                  dt, 0.f, 1);
            else
                gemm_k<<<g3, blk256, 0, stream>>>(x2i, W3i, dq3, b3, H2, kacc, hb, hs,
                                                  hbuf, hb,
                                                  (s == NS - 1) ? nullptr : x0b,
                                                  tend, 0.f, dt / 6.f, 2);
        }
    }
}